// Round 13
// baseline (466.752 us; speedup 1.0000x reference)
//
#include <hip/hip_runtime.h>
#include <hip/hip_bf16.h>
#include <stdint.h>

// NonLocalBlock. Inputs/outputs FLOAT32; bf16 internal. B=16, C=512, N=4096.
// R17: prep_x wide-segment round (4th and final prep_x mechanism).
//  - prep_x: 64x64 tile (128-B read segments) -> 64c x 256n tile: one wave
//    reads a FULL 1-KB row per instruction; XB writes 512-B segments. FETCH
//    showed only 66 MB of 256 MB (L3-served) yet 2.55 TB/s -> segment-width
//    theory. Transpose LDS 32 KB with swz(c)=((c>>3)<<2)^((c&7)<<5):
//    writes aligned 8B + 2 lanes/bank; gathers ~2-4 lanes/bank.
//  - scores_softmax fusion kept from R16 (null perf, fewer launches).
//  - All other kernels byte-identical to R16 (passing, 447.9 us).

typedef unsigned short u16;
typedef __attribute__((ext_vector_type(8))) short frag8;   // 8 bf16 = 4 VGPRs
typedef __attribute__((ext_vector_type(4))) float f32x4;

__device__ __forceinline__ u16 f2bf(float f) {
  union { __hip_bfloat16 h; u16 u; } c; c.h = __float2bfloat16(f); return c.u;
}

// async global->LDS DMA, 16B per lane. LDS dest must be wave-uniform base +
// lane*16 — all call sites use (shared_base + tid*8 u16) which satisfies this.
__device__ __forceinline__ void gl_lds16(const u16* g, u16* l) {
  __builtin_amdgcn_global_load_lds(
      (const __attribute__((address_space(1))) void*)g,
      (__attribute__((address_space(3))) void*)l, 16, 0, 0);
}

#define SCHED0 __builtin_amdgcn_sched_barrier(0)
#define SBAR   __builtin_amdgcn_s_barrier()

// ---------------- prep_x: x f32 -> xT bf16, xb bf16, S rowsums ----------------
// 64c x 256n tile; wave reads full 1-KB rows; LDS transpose with swz(c).
__global__ __launch_bounds__(256) void prep_x(const float* __restrict__ X,
                                              u16* __restrict__ XT,
                                              u16* __restrict__ XB,
                                              float* __restrict__ S) {
  const int b = blockIdx.z;
  const int n0 = blockIdx.x * 256;
  const int c0 = blockIdx.y * 64;
  __shared__ u16 t[64 * 256];            // 32 KB, swizzled cols
  const int tid = threadIdx.x;
  const int lane = tid & 63, wave = tid >> 6;
  const float* Xb = X + (int64_t)b * (512LL * 4096) + n0 + lane * 4;
  u16* XBb = XB + (int64_t)b * (512LL * 4096) + n0 + lane * 4;

#pragma unroll
  for (int g = 0; g < 4; g++) {
    float4 f[4];
    int rr[4];
#pragma unroll
    for (int k = 0; k < 4; k++) {
      rr[k] = wave * 16 + g * 4 + k;
      f[k] = *(const float4*)(Xb + (int64_t)(c0 + rr[k]) * 4096);
    }
#pragma unroll
    for (int k = 0; k < 4; k++) {
      const int r = rr[k];
      union { uint2 d; u16 u[4]; } pk;
      pk.u[0] = f2bf(f[k].x); pk.u[1] = f2bf(f[k].y);
      pk.u[2] = f2bf(f[k].z); pk.u[3] = f2bf(f[k].w);
      *(uint2*)(XBb + (int64_t)(c0 + r) * 4096) = pk.d;
      const int swz = ((r >> 3) << 2) ^ ((r & 7) << 5);
      *(uint2*)&t[r * 256 + ((lane * 4) ^ swz)] = pk.d;
      float s = f[k].x + f[k].y + f[k].z + f[k].w;
      s += __shfl_xor(s, 1); s += __shfl_xor(s, 2); s += __shfl_xor(s, 4);
      s += __shfl_xor(s, 8); s += __shfl_xor(s, 16); s += __shfl_xor(s, 32);
      if (lane == 0) atomicAdd(&S[b * 512 + c0 + r], s);
    }
  }
  __syncthreads();
  // phase 2: xT[n][c] — lane (l&7) covers c-chunk, l>>3 picks n-row.
  const int cs = (lane & 7) * 8;
#pragma unroll
  for (int it = 0; it < 8; it++) {
    const int nr = it * 32 + wave * 8 + (lane >> 3);
    union { uint4 q; u16 u[8]; } o;
#pragma unroll
    for (int j = 0; j < 8; j++) {
      const int c = cs + j;
      const int swz = ((c >> 3) << 2) ^ ((c & 7) << 5);
      o.u[j] = t[c * 256 + (nr ^ swz)];
    }
    *(uint4*)(XT + ((int64_t)b * 4096 + n0 + nr) * 512 + c0 + cs) = o.q;
  }
}

// ------- gram, no split-K, BK=64, XCD-swizzled: G_b = XB_b XB_b^T -------
__constant__ const int g_ty[10] = {0,0,0,0,1,1,1,2,2,3};
__constant__ const int g_tx[10] = {0,1,2,3,1,2,3,2,3,3};

__global__ __launch_bounds__(256) void gram_sk(const u16* __restrict__ XB,
                                               u16* __restrict__ G) {
  const int flat = blockIdx.x;
  const int w = (flat & 7) * 20 + (flat >> 3);
  const int b = w / 10;
  const int tl = w - b * 10;             // 0..9 upper-triangle tile
  const int m0 = g_ty[tl] * 128, n0 = g_tx[tl] * 128;
  const int tid = threadIdx.x;
  const int lane = tid & 63, wave = tid >> 6;
  __shared__ u16 sA[3][8192];            // 3 bufs x [128][64] bf16 = 48 KB
  __shared__ u16 sB[3][8192];
  const u16* Xb = XB + (int64_t)b * (512LL * 4096);

  f32x4 acc[4][4];
#pragma unroll
  for (int i = 0; i < 4; i++)
#pragma unroll
    for (int j = 0; j < 4; j++)
#pragma unroll
      for (int r = 0; r < 4; r++) acc[i][j][r] = 0.0f;

  const int fr = lane & 15;
  const int hi = lane >> 4;
  const int fkx0 = ((hi) ^ (fr & 7)) * 8;
  const int fkx1 = ((4 + hi) ^ (fr & 7)) * 8;
  const int wm = (wave & 1) * 64, wn = (wave >> 1) * 64;

  const int srow = tid >> 3;             // 0..31
  const int scol = (((tid & 7) ^ ((tid >> 3) & 7))) * 8;
  const u16* ArA = Xb + (int64_t)(m0 + srow) * 4096 + scol;
  const u16* BrA = Xb + (int64_t)(n0 + srow) * 4096 + scol;

  auto stage = [&](int t, int buf) {   // 8 DMAs per tile (BK=64)
    const u16* a = ArA + t * 64;
    const u16* bb = BrA + t * 64;
#pragma unroll
    for (int d = 0; d < 4; d++) {
      gl_lds16(a + (int64_t)d * (32 * 4096), sA[buf] + d * 2048 + tid * 8);
      gl_lds16(bb + (int64_t)d * (32 * 4096), sB[buf] + d * 2048 + tid * 8);
    }
  };
  auto comp = [&](int buf) {
#pragma unroll
    for (int kk = 0; kk < 2; kk++) {
      const int fx = kk ? fkx1 : fkx0;
      frag8 af[4], bf[4];
#pragma unroll
      for (int i = 0; i < 4; i++) {
        af[i] = *(const frag8*)(sA[buf] + (wm + i * 16 + fr) * 64 + fx);
        bf[i] = *(const frag8*)(sB[buf] + (wn + i * 16 + fr) * 64 + fx);
      }
#pragma unroll
      for (int i = 0; i < 4; i++)
#pragma unroll
        for (int j = 0; j < 4; j++)
          acc[i][j] = __builtin_amdgcn_mfma_f32_16x16x32_bf16(af[i], bf[j], acc[i][j], 0, 0, 0);
    }
  };

  stage(0, 0); stage(1, 1);            // NT=64 K-tiles (K=4096, BK=64)
  for (int t = 0; t < 62; t++) {
    SCHED0; SBAR; SCHED0;
    stage(t + 2, (t + 2) % 3);
    asm volatile("s_waitcnt vmcnt(16)" ::: "memory");
    SBAR; SCHED0;
    comp(t % 3);
  }
  asm volatile("s_waitcnt vmcnt(0)" ::: "memory");
  SBAR; SCHED0;
  comp(62 % 3); comp(63 % 3);

  u16* Gb = G + (int64_t)b * 262144;
  const int quad = lane >> 4;
#pragma unroll
  for (int i = 0; i < 4; i++)
#pragma unroll
    for (int j = 0; j < 4; j++) {
      const int row0 = m0 + wm + i * 16 + quad * 4;
      const int col = n0 + wn + j * 16 + fr;
      union { u16 u[4]; uint2 v; } mg;
#pragma unroll
      for (int r = 0; r < 4; r++) {
        const u16 h = f2bf(acc[i][j][r]);
        Gb[(int64_t)(row0 + r) * 512 + col] = h;
        mg.u[r] = h;
      }
      if (m0 != n0)
        *(uint2*)(Gb + (int64_t)col * 512 + row0) = mg.v;
    }
}

// ------ 128x128-tile bt GEMM, K=512, 4 waves, depth-3, XCD-swizzled ------
enum { EPI_BF16 = 0, EPI_BF16I = 2 };

template <int EPI>
__global__ __launch_bounds__(256) void gemm128_bt(
    const u16* __restrict__ A, int64_t sAb, int lda,
    const u16* __restrict__ B, int64_t sBb, int ldb,
    void* __restrict__ Cv, int64_t sCb, int ldc) {
  const int flat = blockIdx.x;
  const int w = (flat & 7) * 32 + (flat >> 3);
  const int b = w >> 4;
  const int rem = w & 15;
  const int m0 = (rem >> 2) * 128, n0 = (rem & 3) * 128;
  const int tid = threadIdx.x;
  const int lane = tid & 63, wave = tid >> 6;
  __shared__ u16 sA[4][4096];
  __shared__ u16 sB[4][4096];
  const u16* Ab = A + (int64_t)b * sAb;
  const u16* Bb = B + (int64_t)b * sBb;

  f32x4 acc[4][4];
#pragma unroll
  for (int i = 0; i < 4; i++)
#pragma unroll
    for (int j = 0; j < 4; j++)
#pragma unroll
      for (int r = 0; r < 4; r++) acc[i][j][r] = 0.0f;

  const int srow = tid >> 2;           // 0..63
  const int scol = (((tid & 3) ^ ((tid >> 3) & 3))) * 8;
  const int fr = lane & 15;
  const int fkx = (((lane >> 4) ^ ((fr >> 1) & 3))) * 8;
  const int wm = (wave & 1) * 64, wn = (wave >> 1) * 64;

  const u16* Ar0 = Ab + (int64_t)(m0 + srow) * lda + scol;
  const u16* Ar1 = Ab + (int64_t)(m0 + 64 + srow) * lda + scol;
  const u16* Br0 = Bb + (int64_t)(n0 + srow) * ldb + scol;
  const u16* Br1 = Bb + (int64_t)(n0 + 64 + srow) * ldb + scol;

  auto stage = [&](int t, int buf) {
    gl_lds16(Ar0 + t * 32, sA[buf] + tid * 8);
    gl_lds16(Ar1 + t * 32, sA[buf] + 2048 + tid * 8);
    gl_lds16(Br0 + t * 32, sB[buf] + tid * 8);
    gl_lds16(Br1 + t * 32, sB[buf] + 2048 + tid * 8);
  };
  auto comp = [&](int buf) {
    frag8 af[4], bf[4];
#pragma unroll
    for (int i = 0; i < 4; i++) {
      af[i] = *(const frag8*)(sA[buf] + (wm + i * 16 + fr) * 32 + fkx);
      bf[i] = *(const frag8*)(sB[buf] + (wn + i * 16 + fr) * 32 + fkx);
    }
#pragma unroll
    for (int i = 0; i < 4; i++)
#pragma unroll
      for (int j = 0; j < 4; j++)
        acc[i][j] = __builtin_amdgcn_mfma_f32_16x16x32_bf16(af[i], bf[j], acc[i][j], 0, 0, 0);
  };

  stage(0, 0); stage(1, 1); stage(2, 2);   // NT=16 K-tiles, depth-3
#pragma unroll
  for (int t = 0; t < 13; t++) {
    SCHED0; SBAR; SCHED0;
    stage(t + 3, (t + 3) % 4);
    asm volatile("s_waitcnt vmcnt(12)" ::: "memory");
    SBAR; SCHED0;
    comp(t % 4);
  }
  asm volatile("s_waitcnt vmcnt(8)" ::: "memory");
  SBAR; SCHED0;
  comp(13 % 4);
  asm volatile("s_waitcnt vmcnt(4)" ::: "memory");
  SBAR; SCHED0;
  comp(14 % 4);
  asm volatile("s_waitcnt vmcnt(0)" ::: "memory");
  SBAR; SCHED0;
  comp(15 % 4);

  const int quad = lane >> 4;
#pragma unroll
  for (int i = 0; i < 4; i++)
#pragma unroll
    for (int j = 0; j < 4; j++)
#pragma unroll
      for (int r = 0; r < 4; r++) {
        const int row = m0 + wm + i * 16 + quad * 4 + r;
        const int col = n0 + wn + j * 16 + fr;
        const float a = acc[i][j][r];
        if constexpr (EPI == EPI_BF16) {
          ((u16*)Cv)[(int64_t)b * sCb + (int64_t)row * ldc + col] = f2bf(a);
        } else {  // EPI_BF16I
          ((u16*)Cv)[(int64_t)b * sCb + (int64_t)row * ldc + col] =
              f2bf(a + (row == col ? 1.0f : 0.0f));
        }
      }
}

// ------ fused scores+softmax: BM=32 x BN=512 row-complete, 4 waves ------
__global__ __launch_bounds__(256) void scores_softmax(
    const u16* __restrict__ T1, const u16* __restrict__ Wthetab,
    const float* __restrict__ e_bphi, const float* __restrict__ e_btheta,
    const float* __restrict__ e_uphi, const float* __restrict__ e_utheta,
    const float* __restrict__ bg,
    u16* __restrict__ ATT, float* __restrict__ R) {
  const int flat = blockIdx.x;
  const int w = (flat & 7) * 32 + (flat >> 3);
  const int b = w >> 4;
  const int m0 = (w & 15) * 32;          // 16 row-tiles of 32
  const int tid = threadIdx.x;
  const int lane = tid & 63, wave = tid >> 6;
  const int fr = lane & 15, quad = lane >> 4;
  const int wn = wave * 128;             // wave's 128-col slice

  __shared__ u16 sA[3][1024];            // [32][32] per buf (2 KB)
  __shared__ u16 sB[3][16384];           // [512][32] per buf (32 KB)
  __shared__ float rmax[4][32], rsum[4][32], rsbg[4][32];

  f32x4 acc[2][8];
#pragma unroll
  for (int i = 0; i < 2; i++)
#pragma unroll
    for (int j = 0; j < 8; j++)
#pragma unroll
      for (int r = 0; r < 4; r++) acc[i][j][r] = 0.0f;

  const int srow = tid >> 2;             // 0..63
  const int scol = (((tid & 3) ^ ((tid >> 3) & 3))) * 8;
  const int fkx = (((lane >> 4) ^ ((fr >> 1) & 3))) * 8;

  const u16* Ar = T1 + (int64_t)b * (512LL * 512) + (int64_t)(m0 + (srow & 31)) * 512 + scol;
  const u16* Br = Wthetab + (int64_t)srow * 512 + scol;  // rows srow + d*64

  auto stage = [&](int t, int buf) {     // 8 B-DMAs (+1 A-DMA for tid<128)
    if (tid < 128)
      gl_lds16(Ar + t * 32, sA[buf] + tid * 8);
#pragma unroll
    for (int d = 0; d < 8; d++)
      gl_lds16(Br + (int64_t)d * (64 * 512) + t * 32, sB[buf] + d * 2048 + tid * 8);
  };
  auto comp = [&](int buf) {
    frag8 af[2], bf[8];
#pragma unroll
    for (int i = 0; i < 2; i++)
      af[i] = *(const frag8*)(sA[buf] + (i * 16 + fr) * 32 + fkx);
#pragma unroll
    for (int j = 0; j < 8; j++)
      bf[j] = *(const frag8*)(sB[buf] + (wn + j * 16 + fr) * 32 + fkx);
#pragma unroll
    for (int i = 0; i < 2; i++)
#pragma unroll
      for (int j = 0; j < 8; j++)
        acc[i][j] = __builtin_amdgcn_mfma_f32_16x16x32_bf16(af[i], bf[j], acc[i][j], 0, 0, 0);
  };

  stage(0, 0); stage(1, 1);              // NT=16 K-tiles
#pragma unroll
  for (int t = 0; t < 14; t++) {
    SCHED0; SBAR; SCHED0;
    stage(t + 2, (t + 2) % 3);
    asm volatile("s_waitcnt vmcnt(16)" ::: "memory");
    SBAR; SCHED0;
    comp(t % 3);
  }
  asm volatile("s_waitcnt vmcnt(0)" ::: "memory");
  SBAR; SCHED0;
  comp(14 % 3); comp(15 % 3);

  // ---- epilogue: rank-1 terms + row softmax ----
  float bth[8], uthv[8], bgv[8];
#pragma unroll
  for (int j = 0; j < 8; j++) {
    const int col = wn + j * 16 + fr;
    bth[j] = e_btheta[col];
    uthv[j] = e_utheta[b * 512 + col];
    bgv[j] = bg[col];
  }
  float bph[2][4], uphv[2][4];
#pragma unroll
  for (int i = 0; i < 2; i++)
#pragma unroll
    for (int r = 0; r < 4; r++) {
      const int grow = m0 + i * 16 + quad * 4 + r;
      bph[i][r] = e_bphi[grow];
      uphv[i][r] = e_uphi[b * 512 + grow];
    }
#pragma unroll
  for (int i = 0; i < 2; i++)
#pragma unroll
    for (int j = 0; j < 8; j++)
#pragma unroll
      for (int r = 0; r < 4; r++)
        acc[i][j][r] = (acc[i][j][r] + bph[i][r] * uthv[j] + bth[j] * uphv[i][r] +
                        4096.0f * bph[i][r] * bth[j]) * (1.0f / 512.0f);

  float m8[2][4];
#pragma unroll
  for (int i = 0; i < 2; i++)
#pragma unroll
    for (int r = 0; r < 4; r++) {
      float m = acc[i][0][r];
#pragma unroll
      for (int j = 1; j < 8; j++) m = fmaxf(m, acc[i][j][r]);
      m8[i][r] = m;
    }
#pragma unroll
  for (int off = 1; off < 16; off <<= 1)
#pragma unroll
    for (int i = 0; i < 2; i++)
#pragma unroll
      for (int r = 0; r < 4; r++) m8[i][r] = fmaxf(m8[i][r], __shfl_xor(m8[i][r], off));
  if (fr == 0)
#pragma unroll
    for (int i = 0; i < 2; i++)
#pragma unroll
      for (int r = 0; r < 4; r++) rmax[wave][i * 16 + quad * 4 + r] = m8[i][r];
  __syncthreads();
#pragma unroll
  for (int i = 0; i < 2; i++)
#pragma unroll
    for (int r = 0; r < 4; r++) {
      const int lr = i * 16 + quad * 4 + r;
      float m = rmax[0][lr];
#pragma unroll
      for (int ww = 1; ww < 4; ww++) m = fmaxf(m, rmax[ww][lr]);
      m8[i][r] = m;
    }

  float s8[2][4], g8[2][4];
#pragma unroll
  for (int i = 0; i < 2; i++)
#pragma unroll
    for (int r = 0; r < 4; r++) { s8[i][r] = 0.f; g8[i][r] = 0.f; }
#pragma unroll
  for (int i = 0; i < 2; i++)
#pragma unroll
    for (int j = 0; j < 8; j++)
#pragma unroll
      for (int r = 0; r < 4; r++) {
        const float e = __expf(acc[i][j][r] - m8[i][r]);
        acc[i][j][r] = e;
        s8[i][r] += e;
        g8[i][r] += e * bgv[j];
      }
#pragma unroll
  for (int off = 1; off < 16; off <<= 1)
#pragma unroll
    for (int i = 0; i < 2; i++)
#pragma unroll
      for (int r = 0; r < 4; r++) {
        s8[i][r] += __shfl_xor(s8[i][r], off);
        g8[i][r] += __shfl_xor(g8[i][r], off);
      }
  if (fr == 0)
#pragma unroll
    for (int i = 0; i < 2; i++)
#pragma unroll
      for (int r = 0; r < 4; r++) {
        const int lr = i * 16 + quad * 4 + r;
        rsum[wave][lr] = s8[i][r];
        rsbg[wave][lr] = g8[i][r];
      }
  __syncthreads();
  u16* Ab = ATT + (int64_t)b * (512LL * 1024);
#pragma unroll
  for (int i = 0; i < 2; i++)
#pragma unroll
    for (int r = 0; r < 4; r++) {
      const int lr = i * 16 + quad * 4 + r;
      float tot = rsum[0][lr], gt = rsbg[0][lr];
#pragma unroll
      for (int ww = 1; ww < 4; ww++) { tot += rsum[ww][lr]; gt += rsbg[ww][lr]; }
      const float inv = 1.0f / tot;
      const int grow = m0 + lr;
      if (wave == 0 && fr == 0) R[b * 512 + grow] = gt * inv;
      u16* row = Ab + (int64_t)grow * 1024;
#pragma unroll
      for (int j = 0; j < 8; j++)
        row[wn + j * 16 + fr] = f2bf(acc[i][j][r] * inv);
    }
}

// ---------------- final: out f32 = (M+I) x + v (A=M bf16, B=xT) ----------------
__global__ __launch_bounds__(256) void gemm_final(const u16* __restrict__ M,
                                                  const u16* __restrict__ XT,
                                                  const float* __restrict__ V,
                                                  float* __restrict__ O) {
  const int flat = blockIdx.x;
  const int w = (flat & 7) * 256 + (flat >> 3);
  const int b = w >> 7;                  // 2 batches per XCD
  const int rem = w & 127;
  const int m0 = (rem >> 5) * 128;       // 4 m-tiles
  const int n0 = (rem & 31) * 128;       // 32 n-tiles
  const int tid = threadIdx.x;
  const int lane = tid & 63, wave = tid >> 6;
  __shared__ u16 sA[2][4096];
  __shared__ u16 sB[2][4096];
  const u16* Ab = M + (int64_t)b * 262144;
  const u16* Bb = XT + (int64_t)b * (4096LL * 512);

  f32x4 acc[4][4];
#pragma unroll
  for (int i = 0; i < 4; i++)
#pragma unroll
    for (int j = 0; j < 4; j++)
#pragma unroll
      for (int r = 0; r < 4; r++) acc[i][j][r] = 0.0f;

  const int srow = tid >> 2;
  const int scol = (((tid & 3) ^ ((tid >> 3) & 3))) * 8;
  const int fr = lane & 15;
  const int fkx = (((lane >> 4) ^ ((fr >> 1) & 3))) * 8;
  const int wm = (wave & 1) * 64, wn = (wave >> 1) * 64;

  const u16* Ar0 = Ab + (int64_t)(m0 + srow) * 512 + scol;
  const u16* Ar1 = Ab + (int64_t)(m0 + 64 + srow) * 512 + scol;
  const u16* Br0 = Bb + (int64_t)(n0 + srow) * 512 + scol;
  const u16* Br1 = Bb + (int64_t)(n0 + 64 + srow) * 512 + scol;

  gl_lds16(Ar0, sA[0] + tid * 8);
  gl_lds16(Ar1, sA[0] + 2048 + tid * 8);
  gl_lds16(Br0, sB[0] + tid * 8);
  gl_lds16(Br1, sB[0] + 2048 + tid * 8);
  __syncthreads();

  for (int k0 = 0; k0 < 512; k0 += 32) {
    const int cur = (k0 >> 5) & 1;
    if (k0 + 32 < 512) {
      u16* dA = sA[cur ^ 1];
      u16* dB = sB[cur ^ 1];
      gl_lds16(Ar0 + k0 + 32, dA + tid * 8);
      gl_lds16(Ar1 + k0 + 32, dA + 2048 + tid * 8);
      gl_lds16(Br0 + k0 + 32, dB + tid * 8);
      gl_lds16(Br1 + k0 + 32, dB + 2048 + tid * 8);
    }
    frag8 af[4], bf[4];
#pragma unroll
    for (int i = 0; i < 4; i++) {
      af[i] = *(const frag8*)(sA[cur] + (wm + i * 16 + fr) * 32 + fkx);
      bf[i] = *(const frag8*)(sB[cur] + (wn + i * 16 + fr) * 32 + fkx);
    }
#pragma unroll
    for (int i = 0; i < 4; i++)
#pragma unroll
      for (int j = 0; j < 4; j++)
        acc[i][j] = __builtin_amdgcn_mfma_f32_16x16x32_bf16(af[i], bf[j], acc[i][j], 0, 0, 0);
    __syncthreads();
  }

  const int quad = lane >> 4;
#pragma unroll
  for (int i = 0; i < 4; i++)
#pragma unroll
    for (int j = 0; j < 4; j++)
#pragma unroll
      for (int r = 0; r < 4; r++) {
        const int row = m0 + wm + i * 16 + quad * 4 + r;
        const int col = n0 + wn + j * 16 + fr;
        O[(int64_t)b * (512LL * 4096) + (int64_t)row * 4096 + col] =
            acc[i][j][r] + V[b * 512 + row];
      }
}

// ---------------- small helpers ----------------
__global__ __launch_bounds__(256) void uv_kernel(const float* __restrict__ Wphi,
                                                 const float* __restrict__ Wtheta,
                                                 const float* __restrict__ S,
                                                 float* __restrict__ UPH, float* __restrict__ UTH) {
  const int b = blockIdx.x;
  const int o0 = blockIdx.y * 64;
  const int tid = threadIdx.x;
  __shared__ float s[512];
  s[tid] = S[b * 512 + tid];
  s[tid + 256] = S[b * 512 + tid + 256];
  __syncthreads();
  const int o = o0 + (tid >> 2);
  const int q = tid & 3;
  float a0 = 0.f, a1 = 0.f;
  for (int c = q * 128; c < q * 128 + 128; c += 4) {
    const float4 wa = *(const float4*)(Wphi + (int64_t)o * 512 + c);
    const float4 wb = *(const float4*)(Wtheta + (int64_t)o * 512 + c);
    a0 += wa.x * s[c] + wa.y * s[c + 1] + wa.z * s[c + 2] + wa.w * s[c + 3];
    a1 += wb.x * s[c] + wb.y * s[c + 1] + wb.z * s[c + 2] + wb.w * s[c + 3];
  }
  a0 += __shfl_xor(a0, 1); a0 += __shfl_xor(a0, 2);
  a1 += __shfl_xor(a1, 1); a1 += __shfl_xor(a1, 2);
  if (q == 0) {
    UPH[b * 512 + o] = a0;
    UTH[b * 512 + o] = a1;
  }
}

__global__ __launch_bounds__(256) void v_kernel(const float* __restrict__ Wout,
                                                const float* __restrict__ R,
                                                const float* __restrict__ bout,
                                                float* __restrict__ V) {
  const int b = blockIdx.x;
  const int o0 = blockIdx.y * 64;
  const int tid = threadIdx.x;
  __shared__ float s[512];
  s[tid] = R[b * 512 + tid];
  s[tid + 256] = R[b * 512 + tid + 256];
  __syncthreads();
  const int o = o0 + (tid >> 2);
  const int q = tid & 3;
  float a0 = 0.f;
  for (int c = q * 128; c < q * 128 + 128; c += 4) {
    const float4 wa = *(const float4*)(Wout + (int64_t)o * 512 + c);
    a0 += wa.x * s[c] + wa.y * s[c + 1] + wa.z * s[c + 2] + wa.w * s[c + 3];
  }
  a0 += __shfl_xor(a0, 1); a0 += __shfl_xor(a0, 2);
  if (q == 0) V[b * 512 + o] = a0 + bout[o];
}

__global__ __launch_bounds__(256) void convert_w(const float* __restrict__ W0,
                                                 const float* __restrict__ W1,
                                                 const float* __restrict__ W2,
                                                 u16* __restrict__ O0, u16* __restrict__ O1,
                                                 u16* __restrict__ O2) {
  const int idx = blockIdx.x * 256 + threadIdx.x;
  const int m = idx >> 16;
  const int off = (idx & 65535) * 4;
  const float* src = (m == 0) ? W0 : (m == 1) ? W1 : W2;
  u16* dst = (m == 0) ? O0 : (m == 1) ? O1 : O2;
  const float4 f = *(const float4*)(src + off);
  union { u16 u[4]; uint2 v; } p;
  p.u[0] = f2bf(f.x); p.u[1] = f2bf(f.y); p.u[2] = f2bf(f.z); p.u[3] = f2bf(f.w);
  *(uint2*)(dst + off) = p.v;
}

__global__ void wg_transpose(const float* __restrict__ Wg, u16* __restrict__ WgT) {
  __shared__ float t[16][17];
  const int i0 = blockIdx.y * 16, j0 = blockIdx.x * 16;
  t[threadIdx.y][threadIdx.x] = Wg[(i0 + threadIdx.y) * 512 + j0 + threadIdx.x];
  __syncthreads();
  WgT[(j0 + threadIdx.y) * 512 + i0 + threadIdx.x] = f2bf(t[threadIdx.x][threadIdx.y]);
}

extern "C" void kernel_launch(void* const* d_in, const int* in_sizes, int n_in,
                              void* d_out, int out_size, void* d_ws, size_t ws_size,
                              hipStream_t stream) {
  const float* x      = (const float*)d_in[0];
  const float* Wtheta = (const float*)d_in[1];
  const float* btheta = (const float*)d_in[2];
  const float* Wphi   = (const float*)d_in[3];
  const float* bphi   = (const float*)d_in[4];
  const float* Wg     = (const float*)d_in[5];
  const float* bg     = (const float*)d_in[6];
  const float* Wout   = (const float*)d_in[7];
  const float* bout   = (const float*)d_in[8];

  char* ws = (char*)d_ws;                   // ~98.1 MiB (same as proven R3 budget)
  u16*   xT     = (u16*)(ws + 0);           // 67,108,864
  u16*   G      = (u16*)(ws + 67108864);    //  8,388,608
  u16*   T1     = (u16*)(ws + 75497472);    //  8,388,608
  float* SC     = (float*)(ws + 83886080);  // 16,777,216 (ATT bf16 region)
  u16*   Wphib  = (u16*)(ws + 100663296);
  u16*   Wthetab= (u16*)(ws + 101187584);
  u16*   Woutb  = (u16*)(ws + 101711872);
  u16*   WgTb   = (u16*)(ws + 102236160);
  float* S      = (float*)(ws + 102760448);
  float* UPH    = (float*)(ws + 102793216);
  float* UTH    = (float*)(ws + 102825984);
  float* R      = (float*)(ws + 102858752);
  float* V      = (float*)(ws + 102891520);
  u16* ATT = (u16*)SC;  // bf16 attn, row stride 1024 u16
  u16* Q = G;           // G dead after T1-gemm
  u16* M = T1;          // T1 dead after scores_softmax

  // d_out (134,217,728 B) as mid-pipeline scratch; fully overwritten by gemm_final.
  u16*   XB = (u16*)d_out;                          // 67,108,864: bf16 x

  hipMemsetAsync(S, 0, 32768, stream);
  prep_x<<<dim3(16, 8, 16), 256, 0, stream>>>(x, xT, XB, S);
  uv_kernel<<<dim3(16, 8), 256, 0, stream>>>(Wphi, Wtheta, S, UPH, UTH);
  convert_w<<<768, 256, 0, stream>>>(Wphi, Wtheta, Wout, Wphib, Wthetab, Woutb);
  wg_transpose<<<dim3(32, 32), dim3(16, 16), 0, stream>>>(Wg, WgTb);
  // G_b = XB_b XB_b^T directly in bf16 (no split-K partials, no reduce)
  gram_sk<<<dim3(160), 256, 0, stream>>>(XB, G);
  // T1_b = Wphi G_b (G symmetric -> bt form valid)
  gemm128_bt<EPI_BF16><<<dim3(256), 256, 0, stream>>>(
      Wphib, 0, 512, G, 512LL * 512, 512, T1, 512LL * 512, 512);
  // fused: scores (+rank-1) -> row softmax -> ATT bf16 + R
  scores_softmax<<<dim3(256), 256, 0, stream>>>(
      T1, Wthetab, bphi, btheta, UPH, UTH, bg, ATT, R);
  // Q_b[j,c] = sum_d WgT[j,d] attn[c,d]
  gemm128_bt<EPI_BF16><<<dim3(256), 256, 0, stream>>>(
      WgTb, 0, 512, ATT, 512LL * 1024, 1024, Q, 512LL * 512, 512);
  // M_b = Wout Q (+ I fold for the residual)
  gemm128_bt<EPI_BF16I><<<dim3(256), 256, 0, stream>>>(
      Woutb, 0, 512, Q, 512LL * 512, 512, M, 512LL * 512, 512);
  v_kernel<<<dim3(16, 8), 256, 0, stream>>>(Wout, R, bout, V);
  // out = (M+I) x + v  (reads xT + M only; overwrites all of d_out)
  gemm_final<<<dim3(2048), 256, 0, stream>>>(M, xT, V, (float*)d_out);
}

// Round 14
// 439.267 us; speedup vs baseline: 1.0626x; 1.0626x over previous
//
#include <hip/hip_runtime.h>
#include <hip/hip_bf16.h>
#include <stdint.h>

// NonLocalBlock. Inputs/outputs FLOAT32; bf16 internal. B=16, C=512, N=4096.
// R18: gram wave-count round.
//  - prep_x REVERTED to R15/R16 form (R17 wide-segment theory refuted: total
//    +19us; prep_x closed at ~79us after 4 null mechanisms).
//  - gram_sk: 256 -> 512 threads (8 waves, 2/SIMD). Counters showed 3100
//    cy/iter vs ~160cy MFMA at 1 wave/SIMD (grid 160 = 1 blk/CU): vmcnt
//    stalls leave SIMDs idle. 2 waves/SIMD lets one wave's stall overlap the
//    other's compute/issue. Per-wave 4 DMAs/tile -> depth-2 wait = vmcnt(8).
//    Same tile/BK/swizzle/byte-layout; geometry 4(m)x2(n) waves, acc[2][4].
//  - Everything else byte-identical to R16/R17 (passing).

typedef unsigned short u16;
typedef __attribute__((ext_vector_type(8))) short frag8;   // 8 bf16 = 4 VGPRs
typedef __attribute__((ext_vector_type(4))) float f32x4;

__device__ __forceinline__ u16 f2bf(float f) {
  union { __hip_bfloat16 h; u16 u; } c; c.h = __float2bfloat16(f); return c.u;
}

// async global->LDS DMA, 16B per lane. LDS dest must be wave-uniform base +
// lane*16 — all call sites use (shared_base + tid*8 u16) which satisfies this.
__device__ __forceinline__ void gl_lds16(const u16* g, u16* l) {
  __builtin_amdgcn_global_load_lds(
      (const __attribute__((address_space(1))) void*)g,
      (__attribute__((address_space(3))) void*)l, 16, 0, 0);
}

#define SCHED0 __builtin_amdgcn_sched_barrier(0)
#define SBAR   __builtin_amdgcn_s_barrier()

// ---------------- prep_x: x f32 -> xT bf16, xb bf16, S rowsums ----------------
__global__ __launch_bounds__(256) void prep_x(const float* __restrict__ X,
                                              u16* __restrict__ XT,
                                              u16* __restrict__ XB,
                                              float* __restrict__ S) {
  const int b = blockIdx.z;
  const int n0 = blockIdx.x * 64;
  const int c0 = blockIdx.y * 64;
  __shared__ u16 t[64][72];
  const float* Xb = X + (int64_t)b * (512LL * 4096);
  const int tid = threadIdx.x;
  const int r = tid >> 3;        // 0..31
  const int e8 = (tid & 7) * 8;  // 0..56

  const float* p0 = Xb + (int64_t)(c0 + r) * 4096 + n0 + e8;
  const float* p1 = p0 + 32LL * 4096;
  const float4 f0 = *(const float4*)(p0);
  const float4 f1 = *(const float4*)(p0 + 4);
  const float4 h0 = *(const float4*)(p1);
  const float4 h1 = *(const float4*)(p1 + 4);

  union { uint4 q; u16 u[8]; } pa, pb;
  pa.u[0] = f2bf(f0.x); pa.u[1] = f2bf(f0.y); pa.u[2] = f2bf(f0.z); pa.u[3] = f2bf(f0.w);
  pa.u[4] = f2bf(f1.x); pa.u[5] = f2bf(f1.y); pa.u[6] = f2bf(f1.z); pa.u[7] = f2bf(f1.w);
  pb.u[0] = f2bf(h0.x); pb.u[1] = f2bf(h0.y); pb.u[2] = f2bf(h0.z); pb.u[3] = f2bf(h0.w);
  pb.u[4] = f2bf(h1.x); pb.u[5] = f2bf(h1.y); pb.u[6] = f2bf(h1.z); pb.u[7] = f2bf(h1.w);

  const int rowA = r, rowB = r + 32;
  *(uint4*)(XB + ((int64_t)b * 512 + c0 + rowA) * 4096 + n0 + e8) = pa.q;
  *(uint4*)(XB + ((int64_t)b * 512 + c0 + rowB) * 4096 + n0 + e8) = pb.q;
  *(uint4*)&t[rowA][e8 ^ (rowA & 56)] = pa.q;
  *(uint4*)&t[rowB][e8 ^ (rowB & 56)] = pb.q;

  float sa = f0.x + f0.y + f0.z + f0.w + f1.x + f1.y + f1.z + f1.w;
  float sb = h0.x + h0.y + h0.z + h0.w + h1.x + h1.y + h1.z + h1.w;
  sa += __shfl_xor(sa, 1); sa += __shfl_xor(sa, 2); sa += __shfl_xor(sa, 4);
  sb += __shfl_xor(sb, 1); sb += __shfl_xor(sb, 2); sb += __shfl_xor(sb, 4);
  if ((tid & 7) == 0) {
    atomicAdd(&S[b * 512 + c0 + rowA], sa);
    atomicAdd(&S[b * 512 + c0 + rowB], sb);
  }
  __syncthreads();
#pragma unroll
  for (int p = 0; p < 2; p++) {
    const int nr = p * 32 + r;
    union { uint4 q; u16 u[8]; } o;
#pragma unroll
    for (int j = 0; j < 8; j++)
      o.u[j] = t[e8 + j][nr ^ e8];  // (e8+j)&56 == e8 since j<8, e8%8==0
    *(uint4*)(XT + ((int64_t)b * 4096 + n0 + nr) * 512 + c0 + e8) = o.q;
  }
}

// --- gram, no split-K, BK=64, XCD-swizzled, 512 threads (8 waves) ---
__constant__ const int g_ty[10] = {0,0,0,0,1,1,1,2,2,3};
__constant__ const int g_tx[10] = {0,1,2,3,1,2,3,2,3,3};

__global__ __launch_bounds__(512) void gram_sk(const u16* __restrict__ XB,
                                               u16* __restrict__ G) {
  // bijective XCD swizzle: 160 blocks = 8 XCDs x 20; XCD x owns b = 2x, 2x+1.
  const int flat = blockIdx.x;
  const int w = (flat & 7) * 20 + (flat >> 3);
  const int b = w / 10;
  const int tl = w - b * 10;             // 0..9 upper-triangle tile
  const int m0 = g_ty[tl] * 128, n0 = g_tx[tl] * 128;
  const int tid = threadIdx.x;
  const int lane = tid & 63, wave = tid >> 6;   // 8 waves
  __shared__ u16 sA[3][8192];            // 3 bufs x [128][64] bf16 = 48 KB
  __shared__ u16 sB[3][8192];
  const u16* Xb = XB + (int64_t)b * (512LL * 4096);

  // 8-wave geometry: wm 4 x wn 2; per-wave acc[2][4] (32x64 sub-tile... rows
  // wm..wm+31 via i<2, cols wn..wn+63 via j<4).
  const int wm = (wave & 3) * 32, wn = (wave >> 2) * 64;
  f32x4 acc[2][4];
#pragma unroll
  for (int i = 0; i < 2; i++)
#pragma unroll
    for (int j = 0; j < 4; j++)
#pragma unroll
      for (int r = 0; r < 4; r++) acc[i][j][r] = 0.0f;

  const int fr = lane & 15;
  const int hi = lane >> 4;
  // 128B-row bank swizzle: physical chunk p of row r = data chunk p^(r&7);
  // wm+i*16 is a multiple of 8 -> read XOR folds to per-lane constants.
  const int fkx0 = ((hi) ^ (fr & 7)) * 8;
  const int fkx1 = ((4 + hi) ^ (fr & 7)) * 8;

  // staging (512 threads): row = tid>>3 (0..63), physical chunk tid&7 ->
  // source data chunk (tid&7)^(row&7); each DMA covers 64 rows (8KB).
  const int srow = tid >> 3;
  const int scol = (((tid & 7) ^ ((tid >> 3) & 7))) * 8;
  const u16* ArA = Xb + (int64_t)(m0 + srow) * 4096 + scol;
  const u16* BrA = Xb + (int64_t)(n0 + srow) * 4096 + scol;

  auto stage = [&](int t, int buf) {   // 4 DMAs per tile per thread/wave
    const u16* a = ArA + t * 64;
    const u16* bb = BrA + t * 64;
    gl_lds16(a, sA[buf] + tid * 8);                        // rows 0-63
    gl_lds16(a + 64LL * 4096, sA[buf] + 4096 + tid * 8);   // rows 64-127
    gl_lds16(bb, sB[buf] + tid * 8);
    gl_lds16(bb + 64LL * 4096, sB[buf] + 4096 + tid * 8);
  };
  auto comp = [&](int buf) {
#pragma unroll
    for (int kk = 0; kk < 2; kk++) {
      const int fx = kk ? fkx1 : fkx0;
      frag8 af[2], bf[4];
#pragma unroll
      for (int i = 0; i < 2; i++)
        af[i] = *(const frag8*)(sA[buf] + (wm + i * 16 + fr) * 64 + fx);
#pragma unroll
      for (int j = 0; j < 4; j++)
        bf[j] = *(const frag8*)(sB[buf] + (wn + j * 16 + fr) * 64 + fx);
#pragma unroll
      for (int i = 0; i < 2; i++)
#pragma unroll
        for (int j = 0; j < 4; j++)
          acc[i][j] = __builtin_amdgcn_mfma_f32_16x16x32_bf16(af[i], bf[j], acc[i][j], 0, 0, 0);
    }
  };

  stage(0, 0); stage(1, 1);            // NT=64 K-tiles (K=4096, BK=64)
  for (int t = 0; t < 62; t++) {
    SCHED0; SBAR; SCHED0;              // buf[(t+2)%3] free (read at iter t-1)
    stage(t + 2, (t + 2) % 3);
    asm volatile("s_waitcnt vmcnt(8)" ::: "memory");  // tile t landed (8 newer/wave)
    SBAR; SCHED0;                      // cross-wave: all tile-t DMAs landed
    comp(t % 3);
  }
  asm volatile("s_waitcnt vmcnt(0)" ::: "memory");
  SBAR; SCHED0;
  comp(62 % 3); comp(63 % 3);

  u16* Gb = G + (int64_t)b * 262144;
  const int quad = lane >> 4;
#pragma unroll
  for (int i = 0; i < 2; i++)
#pragma unroll
    for (int j = 0; j < 4; j++) {
      const int row0 = m0 + wm + i * 16 + quad * 4;
      const int col = n0 + wn + j * 16 + fr;
      union { u16 u[4]; uint2 v; } mg;
#pragma unroll
      for (int r = 0; r < 4; r++) {
        const u16 h = f2bf(acc[i][j][r]);
        Gb[(int64_t)(row0 + r) * 512 + col] = h;
        mg.u[r] = h;
      }
      if (m0 != n0)  // mirror (4 contiguous bf16 = 8B store)
        *(uint2*)(Gb + (int64_t)col * 512 + row0) = mg.v;
    }
}

// ------ 128x128-tile bt GEMM, K=512, 4 waves, depth-3, XCD-swizzled ------
enum { EPI_BF16 = 0, EPI_BF16I = 2 };

template <int EPI>
__global__ __launch_bounds__(256) void gemm128_bt(
    const u16* __restrict__ A, int64_t sAb, int lda,
    const u16* __restrict__ B, int64_t sBb, int ldb,
    void* __restrict__ Cv, int64_t sCb, int ldc) {
  const int flat = blockIdx.x;
  const int w = (flat & 7) * 32 + (flat >> 3);
  const int b = w >> 4;
  const int rem = w & 15;
  const int m0 = (rem >> 2) * 128, n0 = (rem & 3) * 128;
  const int tid = threadIdx.x;
  const int lane = tid & 63, wave = tid >> 6;
  __shared__ u16 sA[4][4096];
  __shared__ u16 sB[4][4096];
  const u16* Ab = A + (int64_t)b * sAb;
  const u16* Bb = B + (int64_t)b * sBb;

  f32x4 acc[4][4];
#pragma unroll
  for (int i = 0; i < 4; i++)
#pragma unroll
    for (int j = 0; j < 4; j++)
#pragma unroll
      for (int r = 0; r < 4; r++) acc[i][j][r] = 0.0f;

  const int srow = tid >> 2;           // 0..63
  const int scol = (((tid & 3) ^ ((tid >> 3) & 3))) * 8;
  const int fr = lane & 15;
  const int fkx = (((lane >> 4) ^ ((fr >> 1) & 3))) * 8;
  const int wm = (wave & 1) * 64, wn = (wave >> 1) * 64;

  const u16* Ar0 = Ab + (int64_t)(m0 + srow) * lda + scol;
  const u16* Ar1 = Ab + (int64_t)(m0 + 64 + srow) * lda + scol;
  const u16* Br0 = Bb + (int64_t)(n0 + srow) * ldb + scol;
  const u16* Br1 = Bb + (int64_t)(n0 + 64 + srow) * ldb + scol;

  auto stage = [&](int t, int buf) {
    gl_lds16(Ar0 + t * 32, sA[buf] + tid * 8);
    gl_lds16(Ar1 + t * 32, sA[buf] + 2048 + tid * 8);
    gl_lds16(Br0 + t * 32, sB[buf] + tid * 8);
    gl_lds16(Br1 + t * 32, sB[buf] + 2048 + tid * 8);
  };
  auto comp = [&](int buf) {
    frag8 af[4], bf[4];
#pragma unroll
    for (int i = 0; i < 4; i++) {
      af[i] = *(const frag8*)(sA[buf] + (wm + i * 16 + fr) * 32 + fkx);
      bf[i] = *(const frag8*)(sB[buf] + (wn + i * 16 + fr) * 32 + fkx);
    }
#pragma unroll
    for (int i = 0; i < 4; i++)
#pragma unroll
      for (int j = 0; j < 4; j++)
        acc[i][j] = __builtin_amdgcn_mfma_f32_16x16x32_bf16(af[i], bf[j], acc[i][j], 0, 0, 0);
  };

  stage(0, 0); stage(1, 1); stage(2, 2);   // NT=16 K-tiles, depth-3
#pragma unroll
  for (int t = 0; t < 13; t++) {
    SCHED0; SBAR; SCHED0;
    stage(t + 3, (t + 3) % 4);
    asm volatile("s_waitcnt vmcnt(12)" ::: "memory");
    SBAR; SCHED0;
    comp(t % 4);
  }
  asm volatile("s_waitcnt vmcnt(8)" ::: "memory");
  SBAR; SCHED0;
  comp(13 % 4);
  asm volatile("s_waitcnt vmcnt(4)" ::: "memory");
  SBAR; SCHED0;
  comp(14 % 4);
  asm volatile("s_waitcnt vmcnt(0)" ::: "memory");
  SBAR; SCHED0;
  comp(15 % 4);

  const int quad = lane >> 4;
#pragma unroll
  for (int i = 0; i < 4; i++)
#pragma unroll
    for (int j = 0; j < 4; j++)
#pragma unroll
      for (int r = 0; r < 4; r++) {
        const int row = m0 + wm + i * 16 + quad * 4 + r;
        const int col = n0 + wn + j * 16 + fr;
        const float a = acc[i][j][r];
        if constexpr (EPI == EPI_BF16) {
          ((u16*)Cv)[(int64_t)b * sCb + (int64_t)row * ldc + col] = f2bf(a);
        } else {  // EPI_BF16I
          ((u16*)Cv)[(int64_t)b * sCb + (int64_t)row * ldc + col] =
              f2bf(a + (row == col ? 1.0f : 0.0f));
        }
      }
}

// ------ fused scores+softmax: BM=32 x BN=512 row-complete, 4 waves ------
__global__ __launch_bounds__(256) void scores_softmax(
    const u16* __restrict__ T1, const u16* __restrict__ Wthetab,
    const float* __restrict__ e_bphi, const float* __restrict__ e_btheta,
    const float* __restrict__ e_uphi, const float* __restrict__ e_utheta,
    const float* __restrict__ bg,
    u16* __restrict__ ATT, float* __restrict__ R) {
  const int flat = blockIdx.x;
  const int w = (flat & 7) * 32 + (flat >> 3);
  const int b = w >> 4;
  const int m0 = (w & 15) * 32;          // 16 row-tiles of 32
  const int tid = threadIdx.x;
  const int lane = tid & 63, wave = tid >> 6;
  const int fr = lane & 15, quad = lane >> 4;
  const int wn = wave * 128;             // wave's 128-col slice

  __shared__ u16 sA[3][1024];            // [32][32] per buf (2 KB)
  __shared__ u16 sB[3][16384];           // [512][32] per buf (32 KB)
  __shared__ float rmax[4][32], rsum[4][32], rsbg[4][32];

  f32x4 acc[2][8];
#pragma unroll
  for (int i = 0; i < 2; i++)
#pragma unroll
    for (int j = 0; j < 8; j++)
#pragma unroll
      for (int r = 0; r < 4; r++) acc[i][j][r] = 0.0f;

  const int srow = tid >> 2;             // 0..63
  const int scol = (((tid & 3) ^ ((tid >> 3) & 3))) * 8;
  const int fkx = (((lane >> 4) ^ ((fr >> 1) & 3))) * 8;

  const u16* Ar = T1 + (int64_t)b * (512LL * 512) + (int64_t)(m0 + (srow & 31)) * 512 + scol;
  const u16* Br = Wthetab + (int64_t)srow * 512 + scol;  // rows srow + d*64

  auto stage = [&](int t, int buf) {     // 8 B-DMAs (+1 A-DMA for tid<128)
    if (tid < 128)
      gl_lds16(Ar + t * 32, sA[buf] + tid * 8);
#pragma unroll
    for (int d = 0; d < 8; d++)
      gl_lds16(Br + (int64_t)d * (64 * 512) + t * 32, sB[buf] + d * 2048 + tid * 8);
  };
  auto comp = [&](int buf) {
    frag8 af[2], bf[8];
#pragma unroll
    for (int i = 0; i < 2; i++)
      af[i] = *(const frag8*)(sA[buf] + (i * 16 + fr) * 32 + fkx);
#pragma unroll
    for (int j = 0; j < 8; j++)
      bf[j] = *(const frag8*)(sB[buf] + (wn + j * 16 + fr) * 32 + fkx);
#pragma unroll
    for (int i = 0; i < 2; i++)
#pragma unroll
      for (int j = 0; j < 8; j++)
        acc[i][j] = __builtin_amdgcn_mfma_f32_16x16x32_bf16(af[i], bf[j], acc[i][j], 0, 0, 0);
  };

  stage(0, 0); stage(1, 1);              // NT=16 K-tiles
#pragma unroll
  for (int t = 0; t < 14; t++) {
    SCHED0; SBAR; SCHED0;
    stage(t + 2, (t + 2) % 3);
    asm volatile("s_waitcnt vmcnt(16)" ::: "memory");
    SBAR; SCHED0;
    comp(t % 3);
  }
  asm volatile("s_waitcnt vmcnt(0)" ::: "memory");
  SBAR; SCHED0;
  comp(14 % 3); comp(15 % 3);

  // ---- epilogue: rank-1 terms + row softmax ----
  float bth[8], uthv[8], bgv[8];
#pragma unroll
  for (int j = 0; j < 8; j++) {
    const int col = wn + j * 16 + fr;
    bth[j] = e_btheta[col];
    uthv[j] = e_utheta[b * 512 + col];
    bgv[j] = bg[col];
  }
  float bph[2][4], uphv[2][4];
#pragma unroll
  for (int i = 0; i < 2; i++)
#pragma unroll
    for (int r = 0; r < 4; r++) {
      const int grow = m0 + i * 16 + quad * 4 + r;
      bph[i][r] = e_bphi[grow];
      uphv[i][r] = e_uphi[b * 512 + grow];
    }
#pragma unroll
  for (int i = 0; i < 2; i++)
#pragma unroll
    for (int j = 0; j < 8; j++)
#pragma unroll
      for (int r = 0; r < 4; r++)
        acc[i][j][r] = (acc[i][j][r] + bph[i][r] * uthv[j] + bth[j] * uphv[i][r] +
                        4096.0f * bph[i][r] * bth[j]) * (1.0f / 512.0f);

  float m8[2][4];
#pragma unroll
  for (int i = 0; i < 2; i++)
#pragma unroll
    for (int r = 0; r < 4; r++) {
      float m = acc[i][0][r];
#pragma unroll
      for (int j = 1; j < 8; j++) m = fmaxf(m, acc[i][j][r]);
      m8[i][r] = m;
    }
#pragma unroll
  for (int off = 1; off < 16; off <<= 1)
#pragma unroll
    for (int i = 0; i < 2; i++)
#pragma unroll
      for (int r = 0; r < 4; r++) m8[i][r] = fmaxf(m8[i][r], __shfl_xor(m8[i][r], off));
  if (fr == 0)
#pragma unroll
    for (int i = 0; i < 2; i++)
#pragma unroll
      for (int r = 0; r < 4; r++) rmax[wave][i * 16 + quad * 4 + r] = m8[i][r];
  __syncthreads();
#pragma unroll
  for (int i = 0; i < 2; i++)
#pragma unroll
    for (int r = 0; r < 4; r++) {
      const int lr = i * 16 + quad * 4 + r;
      float m = rmax[0][lr];
#pragma unroll
      for (int ww = 1; ww < 4; ww++) m = fmaxf(m, rmax[ww][lr]);
      m8[i][r] = m;
    }

  float s8[2][4], g8[2][4];
#pragma unroll
  for (int i = 0; i < 2; i++)
#pragma unroll
    for (int r = 0; r < 4; r++) { s8[i][r] = 0.f; g8[i][r] = 0.f; }
#pragma unroll
  for (int i = 0; i < 2; i++)
#pragma unroll
    for (int j = 0; j < 8; j++)
#pragma unroll
      for (int r = 0; r < 4; r++) {
        const float e = __expf(acc[i][j][r] - m8[i][r]);
        acc[i][j][r] = e;
        s8[i][r] += e;
        g8[i][r] += e * bgv[j];
      }
#pragma unroll
  for (int off = 1; off < 16; off <<= 1)
#pragma unroll
    for (int i = 0; i < 2; i++)
#pragma unroll
      for (int r = 0; r < 4; r++) {
        s8[i][r] += __shfl_xor(s8[i][r], off);
        g8[i][r] += __shfl_xor(g8[i][r], off);
      }
  if (fr == 0)
#pragma unroll
    for (int i = 0; i < 2; i++)
#pragma unroll
      for (int r = 0; r < 4; r++) {
        const int lr = i * 16 + quad * 4 + r;
        rsum[wave][lr] = s8[i][r];
        rsbg[wave][lr] = g8[i][r];
      }
  __syncthreads();
  u16* Ab = ATT + (int64_t)b * (512LL * 1024);
#pragma unroll
  for (int i = 0; i < 2; i++)
#pragma unroll
    for (int r = 0; r < 4; r++) {
      const int lr = i * 16 + quad * 4 + r;
      float tot = rsum[0][lr], gt = rsbg[0][lr];
#pragma unroll
      for (int ww = 1; ww < 4; ww++) { tot += rsum[ww][lr]; gt += rsbg[ww][lr]; }
      const float inv = 1.0f / tot;
      const int grow = m0 + lr;
      if (wave == 0 && fr == 0) R[b * 512 + grow] = gt * inv;
      u16* row = Ab + (int64_t)grow * 1024;
#pragma unroll
      for (int j = 0; j < 8; j++)
        row[wn + j * 16 + fr] = f2bf(acc[i][j][r] * inv);
    }
}

// ---------------- final: out f32 = (M+I) x + v (A=M bf16, B=xT) ----------------
__global__ __launch_bounds__(256) void gemm_final(const u16* __restrict__ M,
                                                  const u16* __restrict__ XT,
                                                  const float* __restrict__ V,
                                                  float* __restrict__ O) {
  const int flat = blockIdx.x;
  const int w = (flat & 7) * 256 + (flat >> 3);
  const int b = w >> 7;                  // 2 batches per XCD
  const int rem = w & 127;
  const int m0 = (rem >> 5) * 128;       // 4 m-tiles
  const int n0 = (rem & 31) * 128;       // 32 n-tiles
  const int tid = threadIdx.x;
  const int lane = tid & 63, wave = tid >> 6;
  __shared__ u16 sA[2][4096];
  __shared__ u16 sB[2][4096];
  const u16* Ab = M + (int64_t)b * 262144;
  const u16* Bb = XT + (int64_t)b * (4096LL * 512);

  f32x4 acc[4][4];
#pragma unroll
  for (int i = 0; i < 4; i++)
#pragma unroll
    for (int j = 0; j < 4; j++)
#pragma unroll
      for (int r = 0; r < 4; r++) acc[i][j][r] = 0.0f;

  const int srow = tid >> 2;
  const int scol = (((tid & 3) ^ ((tid >> 3) & 3))) * 8;
  const int fr = lane & 15;
  const int fkx = (((lane >> 4) ^ ((fr >> 1) & 3))) * 8;
  const int wm = (wave & 1) * 64, wn = (wave >> 1) * 64;

  const u16* Ar0 = Ab + (int64_t)(m0 + srow) * 512 + scol;
  const u16* Ar1 = Ab + (int64_t)(m0 + 64 + srow) * 512 + scol;
  const u16* Br0 = Bb + (int64_t)(n0 + srow) * 512 + scol;
  const u16* Br1 = Bb + (int64_t)(n0 + 64 + srow) * 512 + scol;

  gl_lds16(Ar0, sA[0] + tid * 8);
  gl_lds16(Ar1, sA[0] + 2048 + tid * 8);
  gl_lds16(Br0, sB[0] + tid * 8);
  gl_lds16(Br1, sB[0] + 2048 + tid * 8);
  __syncthreads();

  for (int k0 = 0; k0 < 512; k0 += 32) {
    const int cur = (k0 >> 5) & 1;
    if (k0 + 32 < 512) {
      u16* dA = sA[cur ^ 1];
      u16* dB = sB[cur ^ 1];
      gl_lds16(Ar0 + k0 + 32, dA + tid * 8);
      gl_lds16(Ar1 + k0 + 32, dA + 2048 + tid * 8);
      gl_lds16(Br0 + k0 + 32, dB + tid * 8);
      gl_lds16(Br1 + k0 + 32, dB + 2048 + tid * 8);
    }
    frag8 af[4], bf[4];
#pragma unroll
    for (int i = 0; i < 4; i++) {
      af[i] = *(const frag8*)(sA[cur] + (wm + i * 16 + fr) * 32 + fkx);
      bf[i] = *(const frag8*)(sB[cur] + (wn + i * 16 + fr) * 32 + fkx);
    }
#pragma unroll
    for (int i = 0; i < 4; i++)
#pragma unroll
      for (int j = 0; j < 4; j++)
        acc[i][j] = __builtin_amdgcn_mfma_f32_16x16x32_bf16(af[i], bf[j], acc[i][j], 0, 0, 0);
    __syncthreads();
  }

  const int quad = lane >> 4;
#pragma unroll
  for (int i = 0; i < 4; i++)
#pragma unroll
    for (int j = 0; j < 4; j++)
#pragma unroll
      for (int r = 0; r < 4; r++) {
        const int row = m0 + wm + i * 16 + quad * 4 + r;
        const int col = n0 + wn + j * 16 + fr;
        O[(int64_t)b * (512LL * 4096) + (int64_t)row * 4096 + col] =
            acc[i][j][r] + V[b * 512 + row];
      }
}

// ---------------- small helpers ----------------
__global__ __launch_bounds__(256) void uv_kernel(const float* __restrict__ Wphi,
                                                 const float* __restrict__ Wtheta,
                                                 const float* __restrict__ S,
                                                 float* __restrict__ UPH, float* __restrict__ UTH) {
  const int b = blockIdx.x;
  const int o0 = blockIdx.y * 64;
  const int tid = threadIdx.x;
  __shared__ float s[512];
  s[tid] = S[b * 512 + tid];
  s[tid + 256] = S[b * 512 + tid + 256];
  __syncthreads();
  const int o = o0 + (tid >> 2);
  const int q = tid & 3;
  float a0 = 0.f, a1 = 0.f;
  for (int c = q * 128; c < q * 128 + 128; c += 4) {
    const float4 wa = *(const float4*)(Wphi + (int64_t)o * 512 + c);
    const float4 wb = *(const float4*)(Wtheta + (int64_t)o * 512 + c);
    a0 += wa.x * s[c] + wa.y * s[c + 1] + wa.z * s[c + 2] + wa.w * s[c + 3];
    a1 += wb.x * s[c] + wb.y * s[c + 1] + wb.z * s[c + 2] + wb.w * s[c + 3];
  }
  a0 += __shfl_xor(a0, 1); a0 += __shfl_xor(a0, 2);
  a1 += __shfl_xor(a1, 1); a1 += __shfl_xor(a1, 2);
  if (q == 0) {
    UPH[b * 512 + o] = a0;
    UTH[b * 512 + o] = a1;
  }
}

__global__ __launch_bounds__(256) void v_kernel(const float* __restrict__ Wout,
                                                const float* __restrict__ R,
                                                const float* __restrict__ bout,
                                                float* __restrict__ V) {
  const int b = blockIdx.x;
  const int o0 = blockIdx.y * 64;
  const int tid = threadIdx.x;
  __shared__ float s[512];
  s[tid] = R[b * 512 + tid];
  s[tid + 256] = R[b * 512 + tid + 256];
  __syncthreads();
  const int o = o0 + (tid >> 2);
  const int q = tid & 3;
  float a0 = 0.f;
  for (int c = q * 128; c < q * 128 + 128; c += 4) {
    const float4 wa = *(const float4*)(Wout + (int64_t)o * 512 + c);
    a0 += wa.x * s[c] + wa.y * s[c + 1] + wa.z * s[c + 2] + wa.w * s[c + 3];
  }
  a0 += __shfl_xor(a0, 1); a0 += __shfl_xor(a0, 2);
  if (q == 0) V[b * 512 + o] = a0 + bout[o];
}

__global__ __launch_bounds__(256) void convert_w(const float* __restrict__ W0,
                                                 const float* __restrict__ W1,
                                                 const float* __restrict__ W2,
                                                 u16* __restrict__ O0, u16* __restrict__ O1,
                                                 u16* __restrict__ O2) {
  const int idx = blockIdx.x * 256 + threadIdx.x;
  const int m = idx >> 16;
  const int off = (idx & 65535) * 4;
  const float* src = (m == 0) ? W0 : (m == 1) ? W1 : W2;
  u16* dst = (m == 0) ? O0 : (m == 1) ? O1 : O2;
  const float4 f = *(const float4*)(src + off);
  union { u16 u[4]; uint2 v; } p;
  p.u[0] = f2bf(f.x); p.u[1] = f2bf(f.y); p.u[2] = f2bf(f.z); p.u[3] = f2bf(f.w);
  *(uint2*)(dst + off) = p.v;
}

__global__ void wg_transpose(const float* __restrict__ Wg, u16* __restrict__ WgT) {
  __shared__ float t[16][17];
  const int i0 = blockIdx.y * 16, j0 = blockIdx.x * 16;
  t[threadIdx.y][threadIdx.x] = Wg[(i0 + threadIdx.y) * 512 + j0 + threadIdx.x];
  __syncthreads();
  WgT[(j0 + threadIdx.y) * 512 + i0 + threadIdx.x] = f2bf(t[threadIdx.x][threadIdx.y]);
}

extern "C" void kernel_launch(void* const* d_in, const int* in_sizes, int n_in,
                              void* d_out, int out_size, void* d_ws, size_t ws_size,
                              hipStream_t stream) {
  const float* x      = (const float*)d_in[0];
  const float* Wtheta = (const float*)d_in[1];
  const float* btheta = (const float*)d_in[2];
  const float* Wphi   = (const float*)d_in[3];
  const float* bphi   = (const float*)d_in[4];
  const float* Wg     = (const float*)d_in[5];
  const float* bg     = (const float*)d_in[6];
  const float* Wout   = (const float*)d_in[7];
  const float* bout   = (const float*)d_in[8];

  char* ws = (char*)d_ws;                   // ~98.1 MiB (same as proven R3 budget)
  u16*   xT     = (u16*)(ws + 0);           // 67,108,864
  u16*   G      = (u16*)(ws + 67108864);    //  8,388,608
  u16*   T1     = (u16*)(ws + 75497472);    //  8,388,608
  float* SC     = (float*)(ws + 83886080);  // 16,777,216 (ATT bf16 region)
  u16*   Wphib  = (u16*)(ws + 100663296);
  u16*   Wthetab= (u16*)(ws + 101187584);
  u16*   Woutb  = (u16*)(ws + 101711872);
  u16*   WgTb   = (u16*)(ws + 102236160);
  float* S      = (float*)(ws + 102760448);
  float* UPH    = (float*)(ws + 102793216);
  float* UTH    = (float*)(ws + 102825984);
  float* R      = (float*)(ws + 102858752);
  float* V      = (float*)(ws + 102891520);
  u16* ATT = (u16*)SC;  // bf16 attn, row stride 1024 u16
  u16* Q = G;           // G dead after T1-gemm
  u16* M = T1;          // T1 dead after scores_softmax

  // d_out (134,217,728 B) as mid-pipeline scratch; fully overwritten by gemm_final.
  u16*   XB = (u16*)d_out;                          // 67,108,864: bf16 x

  hipMemsetAsync(S, 0, 32768, stream);
  prep_x<<<dim3(64, 8, 16), 256, 0, stream>>>(x, xT, XB, S);
  uv_kernel<<<dim3(16, 8), 256, 0, stream>>>(Wphi, Wtheta, S, UPH, UTH);
  convert_w<<<768, 256, 0, stream>>>(Wphi, Wtheta, Wout, Wphib, Wthetab, Woutb);
  wg_transpose<<<dim3(32, 32), dim3(16, 16), 0, stream>>>(Wg, WgTb);
  // G_b = XB_b XB_b^T directly in bf16 (no split-K partials, no reduce)
  gram_sk<<<dim3(160), 512, 0, stream>>>(XB, G);
  // T1_b = Wphi G_b (G symmetric -> bt form valid)
  gemm128_bt<EPI_BF16><<<dim3(256), 256, 0, stream>>>(
      Wphib, 0, 512, G, 512LL * 512, 512, T1, 512LL * 512, 512);
  // fused: scores (+rank-1) -> row softmax -> ATT bf16 + R
  scores_softmax<<<dim3(256), 256, 0, stream>>>(
      T1, Wthetab, bphi, btheta, UPH, UTH, bg, ATT, R);
  // Q_b[j,c] = sum_d WgT[j,d] attn[c,d]
  gemm128_bt<EPI_BF16><<<dim3(256), 256, 0, stream>>>(
      WgTb, 0, 512, ATT, 512LL * 1024, 1024, Q, 512LL * 512, 512);
  // M_b = Wout Q (+ I fold for the residual)
  gemm128_bt<EPI_BF16I><<<dim3(256), 256, 0, stream>>>(
      Woutb, 0, 512, Q, 512LL * 512, 512, M, 512LL * 512, 512);
  v_kernel<<<dim3(16, 8), 256, 0, stream>>>(Wout, R, bout, V);
  // out = (M+I) x + v  (reads xT + M only; overwrites all of d_out)
  gemm_final<<<dim3(2048), 256, 0, stream>>>(M, xT, V, (float*)d_out);
}